// Round 6
// baseline (175.367 us; speedup 1.0000x reference)
//
#include <hip/hip_runtime.h>

typedef unsigned short ushort_t;
typedef __attribute__((ext_vector_type(8))) short short8;
typedef __attribute__((ext_vector_type(4))) unsigned short ushort4_t;
typedef __attribute__((ext_vector_type(4))) float f32x4;
typedef __attribute__((ext_vector_type(16))) float f32x16;

#define KD 1024
#define ND 1024

__device__ __forceinline__ float b2f(unsigned short u) {
  union { unsigned int i; float f; } x; x.i = ((unsigned int)u) << 16; return x.f;
}
__device__ __forceinline__ unsigned short f2b(float f) {
  union { float f; unsigned int i; } x; x.f = f;
  unsigned int u = x.i;
  unsigned int r = (u + 0x7FFFu + ((u >> 16) & 1u)) >> 16;
  return (unsigned short)r;
}
__device__ __forceinline__ unsigned int cvtpk(float lo, float hi) {
  unsigned int r;
  asm("v_cvt_pk_bf16_f32 %0, %1, %2" : "=v"(r) : "v"(lo), "v"(hi));
  return r;
}
__device__ __forceinline__ void gload16(const void* g, void* l) {
  __builtin_amdgcn_global_load_lds((const __attribute__((address_space(1))) void*)g,
                                   (__attribute__((address_space(3))) void*)l, 16, 0, 0);
}

// f32 -> bf16 conversion
__global__ __launch_bounds__(256) void cvt_kernel(
    const float* __restrict__ s0, const float* __restrict__ s1, const float* __restrict__ s2,
    const float* __restrict__ s3, const float* __restrict__ s4, const float* __restrict__ s5,
    const float* __restrict__ s6,
    ushort_t* __restrict__ d0, ushort_t* __restrict__ d1, ushort_t* __restrict__ d2,
    ushort_t* __restrict__ d3, ushort_t* __restrict__ d4, ushort_t* __restrict__ d5,
    ushort_t* __restrict__ d6)
{
  const int z = blockIdx.z;
  const float* s; ushort_t* d; int n;
  switch (z) {
    case 0: s = s0; d = d0; n = 1 << 22; break;
    case 1: s = s1; d = d1; n = 1 << 22; break;
    case 2: s = s2; d = d2; n = 1 << 22; break;
    case 3: s = s3; d = d3; n = 1 << 20; break;
    case 4: s = s4; d = d4; n = 1 << 20; break;
    case 5: s = s5; d = d5; n = 1 << 20; break;
    default: s = s6; d = d6; n = 1 << 20; break;
  }
  int i = (blockIdx.x * 256 + threadIdx.x) * 4;
  if (i < n) {
    float4 v = *(const float4*)(s + i);
    ushort4_t o = { f2b(v.x), f2b(v.y), f2b(v.z), f2b(v.w) };
    *(ushort4_t*)(d + i) = o;
  }
}

// Mterm[b][i] = (mask[b][i] - min_i mask[b][i]) * (-1e9*log2e) - 32   (f64-exact)
__global__ __launch_bounds__(256) void maskprep_kernel(
    const float* __restrict__ mask, float* __restrict__ Mterm)
{
  __shared__ float red[4];
  const int b = blockIdx.x, tid = threadIdx.x;
  const float* mp = mask + (size_t)b * 2048;
  float lm = 1e30f;
  for (int i = tid; i < 2048; i += 256) lm = fminf(lm, mp[i]);
#pragma unroll
  for (int s2 = 1; s2 < 64; s2 <<= 1) lm = fminf(lm, __shfl_xor(lm, s2));
  if ((tid & 63) == 0) red[tid >> 6] = lm;
  __syncthreads();
  const float mb = fminf(fminf(red[0], red[1]), fminf(red[2], red[3]));
  const double Cd = -1.4426950408889634e9;
  for (int i = tid; i < 2048; i += 256)
    Mterm[b * 2048 + i] = (float)(((double)mp[i] - (double)mb) * Cd) - 32.0f;
}

// C = (A @ W^T + bias) * (z==0 ? oscale : 1).  128x128 tile, BK=64, 4 waves.
__global__ __launch_bounds__(256) void gemm3_kernel(
    const ushort_t* __restrict__ A0, const ushort_t* __restrict__ A1, const ushort_t* __restrict__ A2,
    const ushort_t* __restrict__ W0, const ushort_t* __restrict__ W1, const ushort_t* __restrict__ W2,
    const float* __restrict__ B0, const float* __restrict__ B1, const float* __restrict__ B2,
    ushort_t* __restrict__ C0, ushort_t* __restrict__ C1, ushort_t* __restrict__ C2,
    float* __restrict__ Cf, int head_layout, float oscale)
{
  const int z = blockIdx.z;
  const ushort_t* A  = (z == 0) ? A0 : (z == 1) ? A1 : A2;
  const ushort_t* W  = (z == 0) ? W0 : (z == 1) ? W1 : W2;
  const float*    Bb = (z == 0) ? B0 : (z == 1) ? B1 : B2;
  ushort_t*       C  = (z == 0) ? C0 : (z == 1) ? C1 : C2;
  const float sc = (z == 0) ? oscale : 1.0f;

  __shared__ ushort_t Alds[128 * 64];
  __shared__ ushort_t Blds[128 * 64];

  const int tid = threadIdx.x;
  const int wave = tid >> 6, lane = tid & 63;
  const int g = lane >> 4, c = lane & 15;
  const int wr = (wave >> 1) * 64, wc = (wave & 1) * 64;
  const int rr = lane >> 3, jj = lane & 7;
  const int sj = jj ^ (rr & 7);

  const ushort_t* Abase = A + (size_t)(blockIdx.y * 128) * KD;
  const ushort_t* Wbase = W + (size_t)(blockIdx.x * 128) * KD;

  f32x4 acc[4][4];
#pragma unroll
  for (int m = 0; m < 4; ++m)
#pragma unroll
    for (int n = 0; n < 4; ++n) acc[m][n] = (f32x4){0.f, 0.f, 0.f, 0.f};

  for (int k0 = 0; k0 < KD; k0 += 64) {
    for (int i = wave; i < 16; i += 4) {
      gload16(Abase + (size_t)(i * 8 + rr) * KD + k0 + sj * 8, &Alds[i * 512]);
      gload16(Wbase + (size_t)(i * 8 + rr) * KD + k0 + sj * 8, &Blds[i * 512]);
    }
    __syncthreads();
#pragma unroll
    for (int kk = 0; kk < 2; ++kk) {
      short8 af[4], bf[4];
#pragma unroll
      for (int m = 0; m < 4; ++m) {
        int row = wr + m * 16 + c;
        int blk = (g + 4 * kk) ^ (row & 7);
        af[m] = *(const short8*)&Alds[row * 64 + blk * 8];
      }
#pragma unroll
      for (int n = 0; n < 4; ++n) {
        int row = wc + n * 16 + c;
        int blk = (g + 4 * kk) ^ (row & 7);
        bf[n] = *(const short8*)&Blds[row * 64 + blk * 8];
      }
#pragma unroll
      for (int m = 0; m < 4; ++m)
#pragma unroll
        for (int n = 0; n < 4; ++n)
          acc[m][n] = __builtin_amdgcn_mfma_f32_16x16x32_bf16(af[m], bf[n], acc[m][n], 0, 0, 0);
    }
    __syncthreads();
  }

#pragma unroll
  for (int n = 0; n < 4; ++n) {
    int col = blockIdx.x * 128 + wc + n * 16 + c;
    float bv = Bb[col];
#pragma unroll
    for (int m = 0; m < 4; ++m) {
      int rb = blockIdx.y * 128 + wr + m * 16 + 4 * g;
#pragma unroll
      for (int t = 0; t < 4; ++t) {
        int row = rb + t;
        float v = (acc[m][n][t] + bv) * sc;
        if (head_layout) {
          size_t o = (((size_t)(row >> 11) * 16 + (col >> 6)) * 2048 + (size_t)(row & 2047)) * 64 + (col & 63);
          C[o] = f2b(v);
        } else {
          Cf[(size_t)row * ND + col] = v;
        }
      }
    }
  }
}

// Flash attention v6: 32x32x16 MFMA, swapped QK^T, P fully in-register
// (cvt_pk + shfl_xor(32) exchange), fixed per-batch max from Mterm global,
// double-buffered K (global_load_lds) + Vt (reg-staged), 1 barrier/tile.
// Lane: h = lane>>5, cq = lane&31 (q index within wave's 32 rows).
__global__ __launch_bounds__(256) void attn_kernel(
    const ushort_t* __restrict__ Qh, const ushort_t* __restrict__ Kh,
    const ushort_t* __restrict__ Vh, const float* __restrict__ Mterm,
    ushort_t* __restrict__ out)
{
  __shared__ ushort_t Klds[2][64 * 64];     // [key][64d], chunk-XOR by key&7
  __shared__ unsigned int Vt[2][64 * 32];   // [d][keypair], chunk-XOR by d&7

  const int tid = threadIdx.x;
  const int wave = tid >> 6, lane = tid & 63;
  const int h = lane >> 5, cq = lane & 31;
  const int qblk = blockIdx.x;              // 0..15
  const int bh = blockIdx.y;                // 0..31
  const int b = bh >> 4, hd = bh & 15;

  const ushort_t* Qp = Qh + ((size_t)bh * 2048 + qblk * 128 + wave * 32) * 64;
  const ushort_t* Kp = Kh + (size_t)bh * 2048 * 64;
  const ushort_t* Vp = Vh + (size_t)bh * 2048 * 64;
  const float* Mp = Mterm + (size_t)b * 2048;

  const int rr = lane >> 3, jj = lane & 7;  // K staging
  const int rp = tid & 31, cg = tid >> 5;   // V staging
  const int e7 = cq & 7;

  // Q fragments: B-operand, q = cq, d-chunk 16kk + 8h
  short8 qf[4];
#pragma unroll
  for (int kk = 0; kk < 4; ++kk)
    qf[kk] = *(const short8*)(Qp + (size_t)cq * 64 + kk * 16 + h * 8);

  float lacc = 0.f;
  f32x16 accv[2];
#pragma unroll
  for (int m = 0; m < 2; ++m)
#pragma unroll
    for (int i = 0; i < 16; ++i) accv[m][i] = 0.f;

  // ---- prologue: stage tile 0
  for (int i = wave; i < 8; i += 4)
    gload16(Kp + (size_t)(i * 8 + rr) * 64 + (jj ^ (rr & 7)) * 8, &Klds[0][i * 512]);
  {
    const ushort_t* v0 = Vp + (size_t)(rp * 2) * 64 + cg * 8;
    short8 va = *(const short8*)v0;
    short8 vb = *(const short8*)(v0 + 64);
    const unsigned int* vau = (const unsigned int*)&va;
    const unsigned int* vbu = (const unsigned int*)&vb;
#pragma unroll
    for (int i2 = 0; i2 < 4; ++i2) {
      unsigned int w0 = __builtin_amdgcn_perm(vbu[i2], vau[i2], 0x05040100u);
      unsigned int w1 = __builtin_amdgcn_perm(vbu[i2], vau[i2], 0x07060302u);
      const int d0 = cg * 8 + i2 * 2, d1 = d0 + 1;
      Vt[0][d0 * 32 + (((rp >> 2) ^ (d0 & 7)) << 2) + (rp & 3)] = w0;
      Vt[0][d1 * 32 + (((rp >> 2) ^ (d1 & 7)) << 2) + (rp & 3)] = w1;
    }
  }
  __syncthreads();

  int cur = 0;
  for (int k0 = 0; k0 < 2048; k0 += 64) {
    const int nxt = cur ^ 1;
    const bool more = (k0 + 64) < 2048;
    short8 va, vb;
    if (more) {
      for (int i = wave; i < 8; i += 4)
        gload16(Kp + (size_t)(k0 + 64 + i * 8 + rr) * 64 + (jj ^ (rr & 7)) * 8,
                &Klds[nxt][i * 512]);
      const ushort_t* v0 = Vp + (size_t)(k0 + 64 + rp * 2) * 64 + cg * 8;
      va = *(const short8*)v0;
      vb = *(const short8*)(v0 + 64);
    }

    // ---- C-init from Mterm: sacc[n][4j+r] = Mterm[k0 + 32n + 8j + 4h + r]
    f32x16 sacc[2];
#pragma unroll
    for (int n = 0; n < 2; ++n)
#pragma unroll
      for (int j = 0; j < 4; ++j) {
        f32x4 mi = *(const f32x4*)&Mp[k0 + 32 * n + 8 * j + 4 * h];
        sacc[n][4 * j + 0] = mi[0]; sacc[n][4 * j + 1] = mi[1];
        sacc[n][4 * j + 2] = mi[2]; sacc[n][4 * j + 3] = mi[3];
      }

    // ---- swapped QK^T: sacc[n] = S'[key = 32n + (reg&3)+8(reg>>2)+4h][q = cq]
#pragma unroll
    for (int kk = 0; kk < 4; ++kk)
#pragma unroll
      for (int n = 0; n < 2; ++n) {
        short8 kf = *(const short8*)&Klds[cur][(32 * n + cq) * 64 + (((2 * kk + h) ^ e7) << 3)];
        sacc[n] = __builtin_amdgcn_mfma_f32_32x32x16_bf16(kf, qf[kk], sacc[n], 0, 0, 0);
      }

    // ---- fixed-max softmax, pack to bf16 pairs (all lane-local)
    unsigned int w[2][4][2];
#pragma unroll
    for (int n = 0; n < 2; ++n)
#pragma unroll
      for (int j = 0; j < 4; ++j) {
        float p0 = exp2f(sacc[n][4 * j + 0]);
        float p1 = exp2f(sacc[n][4 * j + 1]);
        float p2 = exp2f(sacc[n][4 * j + 2]);
        float p3 = exp2f(sacc[n][4 * j + 3]);
        lacc += (p0 + p1) + (p2 + p3);
        w[n][j][0] = cvtpk(p0, p1);
        w[n][j][1] = cvtpk(p2, p3);
      }

    // ---- write next V tile (overlapped: loads issued at loop top)
    if (more) {
      const unsigned int* vau = (const unsigned int*)&va;
      const unsigned int* vbu = (const unsigned int*)&vb;
#pragma unroll
      for (int i2 = 0; i2 < 4; ++i2) {
        unsigned int w0 = __builtin_amdgcn_perm(vbu[i2], vau[i2], 0x05040100u);
        unsigned int w1 = __builtin_amdgcn_perm(vbu[i2], vau[i2], 0x07060302u);
        const int d0 = cg * 8 + i2 * 2, d1 = d0 + 1;
        Vt[nxt][d0 * 32 + (((rp >> 2) ^ (d0 & 7)) << 2) + (rp & 3)] = w0;
        Vt[nxt][d1 * 32 + (((rp >> 2) ^ (d1 & 7)) << 2) + (rp & 3)] = w1;
      }
    }

    // ---- P exchange: lane<->lane+32 via shfl_xor(32); build PV B-operand
    short8 pf[4];
#pragma unroll
    for (int kk = 0; kk < 4; ++kk) {
      const int n = kk >> 1, jk = 2 * (kk & 1);
      unsigned int loc0 = h ? w[n][jk + 1][0] : w[n][jk][0];
      unsigned int loc1 = h ? w[n][jk + 1][1] : w[n][jk][1];
      unsigned int snd0 = h ? w[n][jk][0] : w[n][jk + 1][0];
      unsigned int snd1 = h ? w[n][jk][1] : w[n][jk + 1][1];
      unsigned int rcv0 = __shfl_xor(snd0, 32);
      unsigned int rcv1 = __shfl_xor(snd1, 32);
      unsigned int W[4];
      W[0] = h ? rcv0 : loc0;
      W[1] = h ? rcv1 : loc1;
      W[2] = h ? loc0 : rcv0;
      W[3] = h ? loc1 : rcv1;
      pf[kk] = *(const short8*)W;
    }

    // ---- PV: accv[m] = O^T[d = 32m + (reg&3)+8(reg>>2)+4h][q = cq]
#pragma unroll
    for (int kk = 0; kk < 4; ++kk)
#pragma unroll
      for (int m = 0; m < 2; ++m) {
        short8 vf = *(const short8*)&Vt[cur][(32 * m + cq) * 32 + (((2 * kk + h) ^ e7) << 2)];
        accv[m] = __builtin_amdgcn_mfma_f32_32x32x16_bf16(vf, pf[kk], accv[m], 0, 0, 0);
      }
    __syncthreads();
    cur = nxt;
  }

  // ---- epilogue: lane-local normalize + packed stores
  lacc += __shfl_xor(lacc, 32);
  const float inv = 1.0f / lacc;
  const int q = qblk * 128 + wave * 32 + cq;
  const size_t base = ((size_t)b * 2048 + q) * 1024 + hd * 64;
#pragma unroll
  for (int m = 0; m < 2; ++m)
#pragma unroll
    for (int j = 0; j < 4; ++j) {
      unsigned int u0 = cvtpk(accv[m][4 * j + 0] * inv, accv[m][4 * j + 1] * inv);
      unsigned int u1 = cvtpk(accv[m][4 * j + 2] * inv, accv[m][4 * j + 3] * inv);
      *(unsigned long long*)&out[base + 32 * m + 8 * j + 4 * h] =
          (unsigned long long)u0 | ((unsigned long long)u1 << 32);
    }
}

extern "C" void kernel_launch(void* const* d_in, const int* in_sizes, int n_in,
                              void* d_out, int out_size, void* d_ws, size_t ws_size,
                              hipStream_t stream) {
  (void)in_sizes; (void)n_in; (void)out_size; (void)ws_size;
  const float* q    = (const float*)d_in[0];
  const float* k    = (const float*)d_in[1];
  const float* v    = (const float*)d_in[2];
  const float* mask = (const float*)d_in[3];
  const float* Wq   = (const float*)d_in[4];
  const float* bq   = (const float*)d_in[5];
  const float* Wk   = (const float*)d_in[6];
  const float* bk   = (const float*)d_in[7];
  const float* Wv   = (const float*)d_in[8];
  const float* bv   = (const float*)d_in[9];
  const float* Wo   = (const float*)d_in[10];
  const float* bo   = (const float*)d_in[11];
  float* outp = (float*)d_out;

  ushort_t* ws = (ushort_t*)d_ws;
  ushort_t* qb  = ws;
  ushort_t* kb  = ws + 4194304;
  ushort_t* vb  = ws + 8388608;
  ushort_t* Wqb = ws + 12582912;
  ushort_t* Wkb = ws + 13631488;
  ushort_t* Wvb = ws + 14680064;
  ushort_t* Wob = ws + 15728640;
  ushort_t* Qw  = ws + 16777216;
  ushort_t* Kw  = ws + 20971520;
  ushort_t* Vw  = ws + 25165824;
  ushort_t* Aw  = ws;                          // aliases qb (dead after QKV gemm)
  float*    Mterm = (float*)(ws + 29360128);   // 16 KB past prior usage

  dim3 blk(256);
  cvt_kernel<<<dim3(4096, 1, 7), blk, 0, stream>>>(
      q, k, v, Wq, Wk, Wv, Wo, qb, kb, vb, Wqb, Wkb, Wvb, Wob);
  maskprep_kernel<<<dim3(2), blk, 0, stream>>>(mask, Mterm);
  // QKV projections; Q output pre-scaled by 1/(8 ln2) for exp2-domain softmax
  gemm3_kernel<<<dim3(8, 32, 3), blk, 0, stream>>>(
      qb, kb, vb, Wqb, Wkb, Wvb, bq, bk, bv, Qw, Kw, Vw, nullptr, 1, 0.18033688011f);
  attn_kernel<<<dim3(16, 32), blk, 0, stream>>>(Qw, Kw, Vw, Mterm, Aw);
  gemm3_kernel<<<dim3(8, 32, 1), blk, 0, stream>>>(
      Aw, nullptr, nullptr, Wob, nullptr, nullptr, bo, nullptr, nullptr,
      nullptr, nullptr, nullptr, outp, 0, 1.0f);
}